// Round 13
// baseline (134.957 us; speedup 1.0000x reference)
//
#include <hip/hip_runtime.h>
#include <hip/hip_bf16.h>
#include <math.h>

typedef __bf16 bf16_t;
typedef __bf16 bf16x8 __attribute__((ext_vector_type(8)));
typedef __bf16 bf16x4 __attribute__((ext_vector_type(4)));
typedef __bf16 bf16x2 __attribute__((ext_vector_type(2)));
typedef float  f32x4  __attribute__((ext_vector_type(4)));
typedef float  f32x16 __attribute__((ext_vector_type(16)));
typedef unsigned u32x4 __attribute__((ext_vector_type(4)));

#define MFMA16(a, b, c) __builtin_amdgcn_mfma_f32_16x16x32_bf16((a), (b), (c), 0, 0, 0)
#define MFMA32(a, b, c) __builtin_amdgcn_mfma_f32_32x32x16_bf16((a), (b), (c), 0, 0, 0)
#define GLDS16(g, s) __builtin_amdgcn_global_load_lds( \
    (const __attribute__((address_space(1))) void*)(g), \
    (__attribute__((address_space(3))) void*)(s), 16, 0, 0)

#define LOG2E 1.4426950408889634f

// ---------------------------------------------------------------------------
// K0: cast weights fp32 -> bf16.  Wqkv = [wq; wk; wv] (1536 x 512), Wp (512x512)
// ---------------------------------------------------------------------------
__global__ __launch_bounds__(256) void cast_weights(
    const float* __restrict__ wq, const float* __restrict__ wk,
    const float* __restrict__ wv, const float* __restrict__ wp,
    bf16_t* __restrict__ Wqkv, bf16_t* __restrict__ Wp)
{
    const int i = (blockIdx.x * 256 + threadIdx.x) * 4;
#pragma unroll
    for (int j = 0; j < 4; ++j) {
        Wqkv[i + j]          = (bf16_t)wq[i + j];
        Wqkv[262144 + i + j] = (bf16_t)wk[i + j];
        Wqkv[524288 + i + j] = (bf16_t)wv[i + j];
        Wp[i + j]            = (bf16_t)wp[i + j];
    }
}

// ---------------------------------------------------------------------------
// K0b: rel-bias in 32x32 MFMA C-fragment order (swapped: D[row=nk][col=q]):
//   Bias3[h][qt(32)][kt(32)][lane(64)][reg(16)] bf16, pre-scaled by log2(e)
// q = qt*32 + (l&31), nk = kt*32 + (reg&3) + 8*(reg>>2) + 4*(l>>5).
// ---------------------------------------------------------------------------
__global__ __launch_bounds__(256) void bias_kernel(
    const float* __restrict__ pos, bf16_t* __restrict__ Bias3)
{
    const int h  = blockIdx.x >> 5;
    const int qt = blockIdx.x & 31;
    const int t = threadIdx.x;
    const int l = t & 63, ko = t >> 6;
    __shared__ bf16_t ps[32][64];   // rows dy = qt..qt+31, cols dx 0..62

    for (int i = t; i < 32 * 63; i += 256) {
        const int r = i / 63, dx = i - r * 63;
        ps[r][dx] = (bf16_t)(pos[h * 3969 + (qt + r) * 63 + dx] * LOG2E);
    }
    __syncthreads();

    const int qx = l & 31, hi = l >> 5;
#pragma unroll
    for (int kt0 = 0; kt0 < 32; kt0 += 4) {
        const int kt = kt0 + ko;
        const int row = 31 - kt;        // dy - qt
        bf16x8 o0, o1;
#pragma unroll
        for (int reg = 0; reg < 16; ++reg) {
            const int kx = (reg & 3) + 8 * (reg >> 2) + 4 * hi;
            const bf16_t v = ps[row][qx - kx + 31];
            if (reg < 8) o0[reg] = v; else o1[reg - 8] = v;
        }
        bf16_t* outp = Bias3 + ((size_t)(((h * 32 + qt) * 32 + kt) * 64 + l)) * 16;
        *(bf16x8*)outp       = o0;
        *(bf16x8*)(outp + 8) = o1;
    }
}

// ---------------------------------------------------------------------------
// K1: GroupNorm, single-sweep register-resident.  Block = (b,g), 512 threads.
// ---------------------------------------------------------------------------
__global__ __launch_bounds__(512) void gn_kernel(
    const float* __restrict__ x, const float* __restrict__ gamma,
    const float* __restrict__ beta, bf16_t* __restrict__ xnT)
{
    const int blk = blockIdx.x;
    const int b = blk >> 5, g = blk & 31;
    const int t = threadIdx.x;
    const int hi = t >> 8, tl = t & 255;
    __shared__ float red[16];
    const float* base = x + ((size_t)b * 512 + g * 16) * 1024;

    f32x4 v[8];
    float s = 0.f, s2 = 0.f;
#pragma unroll
    for (int it = 0; it < 8; ++it) {
        v[it] = *(const f32x4*)(base + (size_t)hi * 8192 + it * 1024 + tl * 4);
#pragma unroll
        for (int j = 0; j < 4; ++j) { s += v[it][j]; s2 += v[it][j] * v[it][j]; }
    }
#pragma unroll
    for (int m = 1; m < 64; m <<= 1) { s += __shfl_xor(s, m); s2 += __shfl_xor(s2, m); }
    const int w = t >> 6;
    if ((t & 63) == 0) { red[w] = s; red[8 + w] = s2; }
    __syncthreads();
    s = 0.f; s2 = 0.f;
#pragma unroll
    for (int i = 0; i < 8; ++i) { s += red[i]; s2 += red[8 + i]; }
    const float mean = s * (1.f / 16384.f);
    const float var  = fmaxf(s2 * (1.f / 16384.f) - mean * mean, 0.f);
    const float rstd = rsqrtf(var + 1e-6f);

    float ga[8], be[8];
#pragma unroll
    for (int it = 0; it < 8; ++it) {
        const int gc = g * 16 + hi * 8 + it;
        ga[it] = gamma[gc] * rstd;
        be[it] = beta[gc] - mean * ga[it];
    }
#pragma unroll
    for (int j = 0; j < 4; ++j) {
        bf16x8 o;
#pragma unroll
        for (int it = 0; it < 8; ++it)
            o[it] = (bf16_t)(v[it][j] * ga[it] + be[it]);
        *(bf16x8*)(xnT + ((size_t)b * 1024 + tl * 4 + j) * 512 + g * 16 + hi * 8) = o;
    }
}

// ---------------------------------------------------------------------------
// K2/K4: GEMM (unchanged — 3-buffer ring + counted vmcnt).
// ---------------------------------------------------------------------------
__global__ __launch_bounds__(256) void gemm_bt(
    const bf16_t* __restrict__ A, const bf16_t* __restrict__ Bt, int mode,
    int mtiles,
    const float* __restrict__ bias0, const float* __restrict__ bias1,
    const float* __restrict__ bias2,
    const float* __restrict__ x0, float* __restrict__ outF,
    bf16_t* __restrict__ Qb, bf16_t* __restrict__ Kb, bf16_t* __restrict__ Vb)
{
    const int K  = 512;
    const int g  = blockIdx.x;
    const int xcd = g & 7;
    const int i_  = g >> 3;
    const int m_idx = i_ % mtiles;
    const int n_idx = xcd * 8 + i_ / mtiles;
    const int m0 = m_idx * 128;
    const int n0 = n_idx * 128;
    const int t = threadIdx.x;
    const int l = t & 63, w = t >> 6;
    const int wr = w >> 1, wc = w & 1;
    const int lrow = l & 15, lgrp = l >> 4;

    __shared__ __align__(16) char smem_raw[49152];
    bf16_t* Ct = (bf16_t*)smem_raw;           // [128][136] (34816 B)

    f32x4 acc[4][4];
#pragma unroll
    for (int i = 0; i < 4; ++i)
#pragma unroll
        for (int j = 0; j < 4; ++j) acc[i][j] = (f32x4){0.f, 0.f, 0.f, 0.f};

    const bf16_t* gA0 = A  + (size_t)(m0 + w * 16 + (l >> 2)) * K + (l & 3) * 8;
    const bf16_t* gA1 = gA0 + (size_t)64 * K;
    const bf16_t* gB0 = Bt + (size_t)(n0 + w * 16 + (l >> 2)) * K + (l & 3) * 8;
    const bf16_t* gB1 = gB0 + (size_t)64 * K;

#define STAGE(s, k0) do {                                                   \
    bf16_t* As_ = (bf16_t*)(smem_raw + (s) * 16384);                        \
    bf16_t* Bs_ = (bf16_t*)(smem_raw + (s) * 16384 + 8192);                 \
    GLDS16(gA0 + (k0), As_ + w * 512);                                      \
    GLDS16(gA1 + (k0), As_ + 2048 + w * 512);                               \
    GLDS16(gB0 + (k0), Bs_ + w * 512);                                      \
    GLDS16(gB1 + (k0), Bs_ + 2048 + w * 512); } while (0)

    STAGE(0, 0);
    STAGE(1, 32);

#pragma unroll
    for (int tk = 0; tk < 16; ++tk) {
        if (tk < 15) asm volatile("s_waitcnt vmcnt(4)" ::: "memory");
        else         asm volatile("s_waitcnt vmcnt(0)" ::: "memory");
        __builtin_amdgcn_s_barrier();
        __builtin_amdgcn_sched_barrier(0);
        if (tk + 2 < 16) STAGE((tk + 2) % 3, (tk + 2) * 32);
        const bf16_t* Asb = (const bf16_t*)(smem_raw + (tk % 3) * 16384);
        const bf16_t* Bsb = Asb + 4096;
        bf16x8 af[4], bfr[4];
#pragma unroll
        for (int ms = 0; ms < 4; ++ms)
            af[ms] = *(const bf16x8*)&Asb[(wr * 64 + ms * 16 + lrow) * 32 + lgrp * 8];
#pragma unroll
        for (int ns = 0; ns < 4; ++ns)
            bfr[ns] = *(const bf16x8*)&Bsb[(wc * 64 + ns * 16 + lrow) * 32 + lgrp * 8];
        __builtin_amdgcn_s_setprio(1);
#pragma unroll
        for (int ms = 0; ms < 4; ++ms)
#pragma unroll
            for (int ns = 0; ns < 4; ++ns)
                acc[ms][ns] = MFMA16(af[ms], bfr[ns], acc[ms][ns]);
        __builtin_amdgcn_s_setprio(0);
    }
#undef STAGE

    if (mode == 0) {
        const int which = m0 >> 9;
        const int mq = (m0 >> 7) & 3;
        const float* bias = (which == 0) ? bias0 : (which == 1) ? bias1 : bias2;
        const float scl = (which == 0) ? 0.125f * LOG2E : 1.0f;
        const int b   = n_idx >> 3;
        const int nn0 = (n_idx & 7) * 128;

        __syncthreads();
        if (which < 2) {
            bf16_t* Qk = (which == 0) ? Qb : Kb;
#pragma unroll
            for (int ms = 0; ms < 4; ++ms) {
                const int ml = wr * 64 + ms * 16 + lgrp * 4;
#pragma unroll
                for (int ns = 0; ns < 4; ++ns) {
                    const int nl = wc * 64 + ns * 16 + lrow;
                    bf16x4 pk;
#pragma unroll
                    for (int j = 0; j < 4; ++j)
                        pk[j] = (bf16_t)((acc[ms][ns][j] + bias[mq * 128 + ml + j]) * scl);
                    *(bf16x4*)&Ct[nl * 136 + ml] = pk;
                }
            }
            __syncthreads();
#pragma unroll
            for (int it = 0; it < 8; ++it) {
                const int idx = it * 256 + t;
                const int token = idx >> 4, oc = idx & 15;
                const bf16x8 vv8 = *(const bf16x8*)&Ct[token * 136 + oc * 8];
                const int head = mq * 2 + (oc >> 3);
                const int d = (oc & 7) * 8;
                *(bf16x8*)(Qk + (((size_t)b * 8 + head) * 1024 + nn0 + token) * 64 + d) = vv8;
            }
        } else {
#pragma unroll
            for (int ms = 0; ms < 4; ++ms) {
                const int ml = wr * 64 + ms * 16 + lgrp * 4;
#pragma unroll
                for (int ns = 0; ns < 4; ++ns) {
                    const int nl = wc * 64 + ns * 16 + lrow;
#pragma unroll
                    for (int j = 0; j < 4; ++j)
                        Ct[(ml + j) * 136 + nl] =
                            (bf16_t)(acc[ms][ns][j] + bias[mq * 128 + ml + j]);
                }
            }
            __syncthreads();
#pragma unroll
            for (int it = 0; it < 8; ++it) {
                const int idx = it * 256 + t;
                const int o = idx >> 4, nc = idx & 15;
                const bf16x8 vv8 = *(const bf16x8*)&Ct[o * 136 + nc * 8];
                const int head = mq * 2 + (o >> 6);
                const int d = o & 63;
                *(bf16x8*)(Vb + (((size_t)b * 8 + head) * 64 + d) * 1024 + nn0 + nc * 8) = vv8;
            }
        }
    } else {
#pragma unroll
        for (int ms = 0; ms < 4; ++ms) {
#pragma unroll
            for (int ns = 0; ns < 4; ++ns) {
                const int c  = m0 + wr * 64 + ms * 16 + lgrp * 4;
                const int np = n0 + wc * 64 + ns * 16 + lrow;
                const int b = np >> 10, n = np & 1023;
#pragma unroll
                for (int j = 0; j < 4; ++j) {
                    const size_t idx = ((size_t)b * 512 + c + j) * 1024 + n;
                    outF[idx] = acc[ms][ns][j] + bias0[c + j] + x0[idx];
                }
            }
        }
    }
}

// ---------------------------------------------------------------------------
// K3: fused attention, 32x32x16 + in-register softmax, NK-SPLIT wave pairs.
// 8 waves = 4 q-chunks (qc=w&3, 32 q each) x 2 nk-halves (half=w>>2).
// Block covers 128 q; grid (64, 8) = 512 blocks = 2/CU = 4 waves/SIMD
// (fixes r12's 2-waves/SIMD occupancy ceiling; compute per kt unchanged).
// Exact softmax splits over nk: partial O/ts combined via LDS at the end.
// ---------------------------------------------------------------------------
__global__ __launch_bounds__(512, 4) void attn_kernel(
    const bf16_t* __restrict__ Qb, const bf16_t* __restrict__ Kb,
    const bf16_t* __restrict__ Vb, const bf16_t* __restrict__ Bias3,
    bf16_t* __restrict__ Xo)
{
    const int bh = blockIdx.x;
    const int h  = bh & 7;
    const int q0 = blockIdx.y * 128;
    const int t = threadIdx.x;
    const int w = t >> 6, l = t & 63;
    const int qc = w & 3, half = w >> 2;
    const int lq = l & 31, hi = l >> 5;

    __shared__ __align__(16) char smem[35840];
    bf16_t* Ks = (bf16_t*)smem;               // [128][72]
    bf16_t* Vs = (bf16_t*)(smem + 18432);     // [64][136]
    float*  comb = (float*)smem;              // [4][64][33] (reused at end)

    // Q fragments (B-op): col=q=l&31, k-chunk d = dc*16 + hi*8
    const int qrow = q0 + qc * 32 + lq;
    const bf16_t* qbase = Qb + ((size_t)bh * 1024 + qrow) * 64;
    bf16x8 qf[4];
#pragma unroll
    for (int dc = 0; dc < 4; ++dc)
        qf[dc] = *(const bf16x8*)(qbase + dc * 16 + hi * 8);

    // bias base: qt = q0/32 + qc; this wave's kt tiles: it*4 + half*2 + {0,1}
    const bf16_t* bbase = Bias3 +
        ((size_t)((h * 32 + (q0 >> 5) + qc) * 32)) * 1024 + (size_t)l * 16;

    bf16x8 ones;
#pragma unroll
    for (int i = 0; i < 8; ++i) ones[i] = (bf16_t)1.0f;

    f32x16 oacc[2], tsacc;
#pragma unroll
    for (int j = 0; j < 16; ++j) { oacc[0][j] = 0.f; oacc[1][j] = 0.f; tsacc[j] = 0.f; }

    const int sr2 = t >> 3;
    const int sc2 = (t & 7) * 8;
    const bf16_t* Kg = Kb + ((size_t)bh * 1024 + sr2) * 64 + sc2;   // [nk][d]
    const bf16_t* Vg = Vb + ((size_t)bh * 64 + sr2) * 1024 + sc2;   // [d][nk]

    // prologue: prefetch double-tile 0 (K 128 rows, V 128 cols) + bias
    bf16x8 kv0 = *(const bf16x8*)(Kg);
    bf16x8 kv1 = *(const bf16x8*)(Kg + (size_t)64 * 64);
    bf16x8 vv0 = *(const bf16x8*)(Vg);
    bf16x8 vv1 = *(const bf16x8*)(Vg + 64);
    bf16x8 bA[4], bB[4];
#pragma unroll
    for (int k = 0; k < 2; ++k) {
        bA[2 * k]     = *(const bf16x8*)(bbase + (size_t)(half * 2 + k) * 1024);
        bA[2 * k + 1] = *(const bf16x8*)(bbase + (size_t)(half * 2 + k) * 1024 + 8);
    }

    auto dtile = [&](int it, bf16x8 (&bcur)[4], bf16x8 (&bnxt)[4]) {
        const int nk0 = it * 128;
        __syncthreads();                 // prev double-tile's LDS reads done
        *(bf16x8*)&Ks[(sr2) * 72 + sc2]      = kv0;
        *(bf16x8*)&Ks[(64 + sr2) * 72 + sc2] = kv1;
        *(bf16x8*)&Vs[sr2 * 136 + sc2]       = vv0;
        *(bf16x8*)&Vs[sr2 * 136 + 64 + sc2]  = vv1;
        __syncthreads();                 // LDS visible to all waves
        if (it < 7) {                    // prefetch double-tile it+1
            const int nkn = nk0 + 128;
#pragma unroll
            for (int k = 0; k < 2; ++k) {
                const size_t tkn = (size_t)((it + 1) * 4 + half * 2 + k) * 1024;
                bnxt[2 * k]     = *(const bf16x8*)(bbase + tkn);
                bnxt[2 * k + 1] = *(const bf16x8*)(bbase + tkn + 8);
            }
            kv0 = *(const bf16x8*)(Kg + (size_t)nkn * 64);
            kv1 = *(const bf16x8*)(Kg + (size_t)(nkn + 64) * 64);
            vv0 = *(const bf16x8*)(Vg + nkn);
            vv1 = *(const bf16x8*)(Vg + nkn + 64);
        }

#pragma unroll
        for (int ktl = 0; ktl < 2; ++ktl) {
            const int ktloc = half * 64 + ktl * 32;
            // S^T = K Q^T + bias  (C-init from bias fragment regs)
            f32x16 sa;
#pragma unroll
            for (int r = 0; r < 8; ++r) {
                sa[r]     = (float)bcur[2 * ktl][r];
                sa[8 + r] = (float)bcur[2 * ktl + 1][r];
            }
#pragma unroll
            for (int dc = 0; dc < 4; ++dc) {
                const bf16x8 kf = *(const bf16x8*)&Ks[(ktloc + lq) * 72 + dc * 16 + hi * 8];
                sa = MFMA32(kf, qf[dc], sa);
            }
            // p = exp2(s): 16 values; pack into 8 bf16x2 words
            unsigned W00, W01, W10, W11, W20, W21, W30, W31;
            {
                float p[16];
#pragma unroll
                for (int r = 0; r < 16; ++r) p[r] = exp2f(sa[r]);
                bf16x2 tw;
#define PACKW(dst, a, b_) { tw[0] = (bf16_t)p[a]; tw[1] = (bf16_t)p[b_]; \
                            dst = __builtin_bit_cast(unsigned, tw); }
                PACKW(W00, 0, 1)   PACKW(W01, 2, 3)
                PACKW(W10, 4, 5)   PACKW(W11, 6, 7)
                PACKW(W20, 8, 9)   PACKW(W21, 10, 11)
                PACKW(W30, 12, 13) PACKW(W31, 14, 15)
#undef PACKW
            }
            // lane-half exchange into PV B-fragment layout
            asm volatile("v_permlane32_swap_b32 %0, %1" : "+v"(W00), "+v"(W10));
            asm volatile("v_permlane32_swap_b32 %0, %1" : "+v"(W01), "+v"(W11));
            asm volatile("v_permlane32_swap_b32 %0, %1" : "+v"(W20), "+v"(W30));
            asm volatile("v_permlane32_swap_b32 %0, %1" : "+v"(W21), "+v"(W31));
            const bf16x8 pf0 = __builtin_bit_cast(bf16x8, (u32x4){W00, W01, W10, W11});
            const bf16x8 pf1 = __builtin_bit_cast(bf16x8, (u32x4){W20, W21, W30, W31});

            // ts(q) += sum_nk P
            tsacc = MFMA32(ones, pf0, tsacc);
            tsacc = MFMA32(ones, pf1, tsacc);
            // PV: out^T[d][q] += V^T[d][nk] P^T[nk][q]
#pragma unroll
            for (int dh = 0; dh < 2; ++dh) {
                const bf16x8 vf0 = *(const bf16x8*)&Vs[(dh * 32 + lq) * 136 + ktloc + hi * 8];
                const bf16x8 vf1 = *(const bf16x8*)&Vs[(dh * 32 + lq) * 136 + ktloc + 16 + hi * 8];
                oacc[dh] = MFMA32(vf0, pf0, oacc[dh]);
                oacc[dh] = MFMA32(vf1, pf1, oacc[dh]);
            }
        }
    };

    for (int it2 = 0; it2 < 8; it2 += 2) {
        dtile(it2,     bA, bB);
        dtile(it2 + 1, bB, bA);
    }

    // combine nk-halves: waves 4-7 publish partials, waves 0-3 reduce+store
    __syncthreads();                      // all compute done; Ks/Vs free
    if (half == 1) {
        float* p = comb + ((size_t)qc * 64 + l) * 33;
#pragma unroll
        for (int j = 0; j < 16; ++j) { p[j] = oacc[0][j]; p[16 + j] = oacc[1][j]; }
        p[32] = tsacc[0];
    }
    __syncthreads();
    if (half == 0) {
        const float* p = comb + ((size_t)qc * 64 + l) * 33;
#pragma unroll
        for (int j = 0; j < 16; ++j) { oacc[0][j] += p[j]; oacc[1][j] += p[16 + j]; }
        const float inv = 1.0f / (tsacc[0] + p[32]);

        const int b = bh >> 3;
        const int q = q0 + qc * 32 + lq;
        bf16_t* xrow = Xo + ((size_t)b * 1024 + q) * 512 + h * 64;
#pragma unroll
        for (int dh = 0; dh < 2; ++dh)
#pragma unroll
            for (int rr = 0; rr < 4; ++rr) {
                bf16x4 o4;
#pragma unroll
                for (int j = 0; j < 4; ++j)
                    o4[j] = (bf16_t)(oacc[dh][4 * rr + j] * inv);
                *(bf16x4*)(xrow + dh * 32 + 8 * rr + 4 * hi) = o4;
            }
    }
}

// ---------------------------------------------------------------------------
extern "C" void kernel_launch(void* const* d_in, const int* in_sizes, int n_in,
                              void* d_out, int out_size, void* d_ws, size_t ws_size,
                              hipStream_t stream)
{
    const float* x     = (const float*)d_in[0];
    const float* gamma = (const float*)d_in[3];
    const float* beta  = (const float*)d_in[4];
    const float* wq    = (const float*)d_in[5];
    const float* bq    = (const float*)d_in[6];
    const float* wk    = (const float*)d_in[7];
    const float* bk    = (const float*)d_in[8];
    const float* wv    = (const float*)d_in[9];
    const float* bv    = (const float*)d_in[10];
    const float* wp    = (const float*)d_in[11];
    const float* bp    = (const float*)d_in[12];
    const float* pos   = (const float*)d_in[13];
    float* out = (float*)d_out;

    size_t off = 0;
    char* wsb = (char*)d_ws;
    auto alloc = [&](size_t bytes) { char* p = wsb + off; off += bytes; return p; };
    bf16_t* Wqkv  = (bf16_t*)alloc((size_t)1536 * 512 * 2);
    bf16_t* Wp    = (bf16_t*)alloc((size_t)512 * 512 * 2);
    bf16_t* xnT   = (bf16_t*)alloc((size_t)8192 * 512 * 2);
    bf16_t* Qb    = (bf16_t*)alloc((size_t)8192 * 512 * 2);
    bf16_t* Kb    = (bf16_t*)alloc((size_t)8192 * 512 * 2);
    bf16_t* Vb    = (bf16_t*)alloc((size_t)8192 * 512 * 2);
    bf16_t* Xo    = (bf16_t*)alloc((size_t)8192 * 512 * 2);
    bf16_t* Bias3 = (bf16_t*)alloc((size_t)8 * 32 * 32 * 64 * 16 * 2);

    hipLaunchKernelGGL(cast_weights, dim3(256), dim3(256), 0, stream,
                       wq, wk, wv, wp, Wqkv, Wp);
    hipLaunchKernelGGL(bias_kernel, dim3(256), dim3(256), 0, stream, pos, Bias3);
    hipLaunchKernelGGL(gn_kernel, dim3(256), dim3(512), 0, stream,
                       x, gamma, beta, xnT);
    hipLaunchKernelGGL(gemm_bt, dim3(768), dim3(256), 0, stream,
                       Wqkv, xnT, 0, 12, bq, bk, bv,
                       nullptr, nullptr, Qb, Kb, Vb);
    hipLaunchKernelGGL(attn_kernel, dim3(64, 8), dim3(512), 0, stream,
                       Qb, Kb, Vb, Bias3, Xo);
    hipLaunchKernelGGL(gemm_bt, dim3(256), dim3(256), 0, stream,
                       Wp, Xo, 1, 4, bp, nullptr, nullptr,
                       x, out, nullptr, nullptr, nullptr);
}

// Round 14
// 98.119 us; speedup vs baseline: 1.3754x; 1.3754x over previous
//
#include <hip/hip_runtime.h>
#include <hip/hip_bf16.h>
#include <math.h>

typedef __bf16 bf16_t;
typedef __bf16 bf16x8 __attribute__((ext_vector_type(8)));
typedef __bf16 bf16x4 __attribute__((ext_vector_type(4)));
typedef __bf16 bf16x2 __attribute__((ext_vector_type(2)));
typedef float  f32x4  __attribute__((ext_vector_type(4)));
typedef float  f32x16 __attribute__((ext_vector_type(16)));
typedef unsigned u32x4 __attribute__((ext_vector_type(4)));

#define MFMA16(a, b, c) __builtin_amdgcn_mfma_f32_16x16x32_bf16((a), (b), (c), 0, 0, 0)
#define MFMA32(a, b, c) __builtin_amdgcn_mfma_f32_32x32x16_bf16((a), (b), (c), 0, 0, 0)
#define GLDS16(g, s) __builtin_amdgcn_global_load_lds( \
    (const __attribute__((address_space(1))) void*)(g), \
    (__attribute__((address_space(3))) void*)(s), 16, 0, 0)

#define LOG2E 1.4426950408889634f

// ---------------------------------------------------------------------------
// K0: cast weights fp32 -> bf16.  Wqkv = [wq; wk; wv] (1536 x 512), Wp (512x512)
// ---------------------------------------------------------------------------
__global__ __launch_bounds__(256) void cast_weights(
    const float* __restrict__ wq, const float* __restrict__ wk,
    const float* __restrict__ wv, const float* __restrict__ wp,
    bf16_t* __restrict__ Wqkv, bf16_t* __restrict__ Wp)
{
    const int i = (blockIdx.x * 256 + threadIdx.x) * 4;
#pragma unroll
    for (int j = 0; j < 4; ++j) {
        Wqkv[i + j]          = (bf16_t)wq[i + j];
        Wqkv[262144 + i + j] = (bf16_t)wk[i + j];
        Wqkv[524288 + i + j] = (bf16_t)wv[i + j];
        Wp[i + j]            = (bf16_t)wp[i + j];
    }
}

// ---------------------------------------------------------------------------
// K0b: rel-bias in 32x32 MFMA C-fragment order (swapped: D[row=nk][col=q]):
//   Bias3[h][qt(32)][kt(32)][lane(64)][reg(16)] bf16, pre-scaled by log2(e)
// q = qt*32 + (l&31), nk = kt*32 + (reg&3) + 8*(reg>>2) + 4*(l>>5).
// ---------------------------------------------------------------------------
__global__ __launch_bounds__(256) void bias_kernel(
    const float* __restrict__ pos, bf16_t* __restrict__ Bias3)
{
    const int h  = blockIdx.x >> 5;
    const int qt = blockIdx.x & 31;
    const int t = threadIdx.x;
    const int l = t & 63, ko = t >> 6;
    __shared__ bf16_t ps[32][64];   // rows dy = qt..qt+31, cols dx 0..62

    for (int i = t; i < 32 * 63; i += 256) {
        const int r = i / 63, dx = i - r * 63;
        ps[r][dx] = (bf16_t)(pos[h * 3969 + (qt + r) * 63 + dx] * LOG2E);
    }
    __syncthreads();

    const int qx = l & 31, hi = l >> 5;
#pragma unroll
    for (int kt0 = 0; kt0 < 32; kt0 += 4) {
        const int kt = kt0 + ko;
        const int row = 31 - kt;        // dy - qt
        bf16x8 o0, o1;
#pragma unroll
        for (int reg = 0; reg < 16; ++reg) {
            const int kx = (reg & 3) + 8 * (reg >> 2) + 4 * hi;
            const bf16_t v = ps[row][qx - kx + 31];
            if (reg < 8) o0[reg] = v; else o1[reg - 8] = v;
        }
        bf16_t* outp = Bias3 + ((size_t)(((h * 32 + qt) * 32 + kt) * 64 + l)) * 16;
        *(bf16x8*)outp       = o0;
        *(bf16x8*)(outp + 8) = o1;
    }
}

// ---------------------------------------------------------------------------
// K1: GroupNorm, single-sweep register-resident.  Block = (b,g), 512 threads.
// ---------------------------------------------------------------------------
__global__ __launch_bounds__(512) void gn_kernel(
    const float* __restrict__ x, const float* __restrict__ gamma,
    const float* __restrict__ beta, bf16_t* __restrict__ xnT)
{
    const int blk = blockIdx.x;
    const int b = blk >> 5, g = blk & 31;
    const int t = threadIdx.x;
    const int hi = t >> 8, tl = t & 255;
    __shared__ float red[16];
    const float* base = x + ((size_t)b * 512 + g * 16) * 1024;

    f32x4 v[8];
    float s = 0.f, s2 = 0.f;
#pragma unroll
    for (int it = 0; it < 8; ++it) {
        v[it] = *(const f32x4*)(base + (size_t)hi * 8192 + it * 1024 + tl * 4);
#pragma unroll
        for (int j = 0; j < 4; ++j) { s += v[it][j]; s2 += v[it][j] * v[it][j]; }
    }
#pragma unroll
    for (int m = 1; m < 64; m <<= 1) { s += __shfl_xor(s, m); s2 += __shfl_xor(s2, m); }
    const int w = t >> 6;
    if ((t & 63) == 0) { red[w] = s; red[8 + w] = s2; }
    __syncthreads();
    s = 0.f; s2 = 0.f;
#pragma unroll
    for (int i = 0; i < 8; ++i) { s += red[i]; s2 += red[8 + i]; }
    const float mean = s * (1.f / 16384.f);
    const float var  = fmaxf(s2 * (1.f / 16384.f) - mean * mean, 0.f);
    const float rstd = rsqrtf(var + 1e-6f);

    float ga[8], be[8];
#pragma unroll
    for (int it = 0; it < 8; ++it) {
        const int gc = g * 16 + hi * 8 + it;
        ga[it] = gamma[gc] * rstd;
        be[it] = beta[gc] - mean * ga[it];
    }
#pragma unroll
    for (int j = 0; j < 4; ++j) {
        bf16x8 o;
#pragma unroll
        for (int it = 0; it < 8; ++it)
            o[it] = (bf16_t)(v[it][j] * ga[it] + be[it]);
        *(bf16x8*)(xnT + ((size_t)b * 1024 + tl * 4 + j) * 512 + g * 16 + hi * 8) = o;
    }
}

// ---------------------------------------------------------------------------
// K2/K4: GEMM (unchanged — 3-buffer ring + counted vmcnt).
// ---------------------------------------------------------------------------
__global__ __launch_bounds__(256) void gemm_bt(
    const bf16_t* __restrict__ A, const bf16_t* __restrict__ Bt, int mode,
    int mtiles,
    const float* __restrict__ bias0, const float* __restrict__ bias1,
    const float* __restrict__ bias2,
    const float* __restrict__ x0, float* __restrict__ outF,
    bf16_t* __restrict__ Qb, bf16_t* __restrict__ Kb, bf16_t* __restrict__ Vb)
{
    const int K  = 512;
    const int g  = blockIdx.x;
    const int xcd = g & 7;
    const int i_  = g >> 3;
    const int m_idx = i_ % mtiles;
    const int n_idx = xcd * 8 + i_ / mtiles;
    const int m0 = m_idx * 128;
    const int n0 = n_idx * 128;
    const int t = threadIdx.x;
    const int l = t & 63, w = t >> 6;
    const int wr = w >> 1, wc = w & 1;
    const int lrow = l & 15, lgrp = l >> 4;

    __shared__ __align__(16) char smem_raw[49152];
    bf16_t* Ct = (bf16_t*)smem_raw;           // [128][136] (34816 B)

    f32x4 acc[4][4];
#pragma unroll
    for (int i = 0; i < 4; ++i)
#pragma unroll
        for (int j = 0; j < 4; ++j) acc[i][j] = (f32x4){0.f, 0.f, 0.f, 0.f};

    const bf16_t* gA0 = A  + (size_t)(m0 + w * 16 + (l >> 2)) * K + (l & 3) * 8;
    const bf16_t* gA1 = gA0 + (size_t)64 * K;
    const bf16_t* gB0 = Bt + (size_t)(n0 + w * 16 + (l >> 2)) * K + (l & 3) * 8;
    const bf16_t* gB1 = gB0 + (size_t)64 * K;

#define STAGE(s, k0) do {                                                   \
    bf16_t* As_ = (bf16_t*)(smem_raw + (s) * 16384);                        \
    bf16_t* Bs_ = (bf16_t*)(smem_raw + (s) * 16384 + 8192);                 \
    GLDS16(gA0 + (k0), As_ + w * 512);                                      \
    GLDS16(gA1 + (k0), As_ + 2048 + w * 512);                               \
    GLDS16(gB0 + (k0), Bs_ + w * 512);                                      \
    GLDS16(gB1 + (k0), Bs_ + 2048 + w * 512); } while (0)

    STAGE(0, 0);
    STAGE(1, 32);

#pragma unroll
    for (int tk = 0; tk < 16; ++tk) {
        if (tk < 15) asm volatile("s_waitcnt vmcnt(4)" ::: "memory");
        else         asm volatile("s_waitcnt vmcnt(0)" ::: "memory");
        __builtin_amdgcn_s_barrier();
        __builtin_amdgcn_sched_barrier(0);
        if (tk + 2 < 16) STAGE((tk + 2) % 3, (tk + 2) * 32);
        const bf16_t* Asb = (const bf16_t*)(smem_raw + (tk % 3) * 16384);
        const bf16_t* Bsb = Asb + 4096;
        bf16x8 af[4], bfr[4];
#pragma unroll
        for (int ms = 0; ms < 4; ++ms)
            af[ms] = *(const bf16x8*)&Asb[(wr * 64 + ms * 16 + lrow) * 32 + lgrp * 8];
#pragma unroll
        for (int ns = 0; ns < 4; ++ns)
            bfr[ns] = *(const bf16x8*)&Bsb[(wc * 64 + ns * 16 + lrow) * 32 + lgrp * 8];
        __builtin_amdgcn_s_setprio(1);
#pragma unroll
        for (int ms = 0; ms < 4; ++ms)
#pragma unroll
            for (int ns = 0; ns < 4; ++ns)
                acc[ms][ns] = MFMA16(af[ms], bfr[ns], acc[ms][ns]);
        __builtin_amdgcn_s_setprio(0);
    }
#undef STAGE

    if (mode == 0) {
        const int which = m0 >> 9;
        const int mq = (m0 >> 7) & 3;
        const float* bias = (which == 0) ? bias0 : (which == 1) ? bias1 : bias2;
        const float scl = (which == 0) ? 0.125f * LOG2E : 1.0f;
        const int b   = n_idx >> 3;
        const int nn0 = (n_idx & 7) * 128;

        __syncthreads();
        if (which < 2) {
            bf16_t* Qk = (which == 0) ? Qb : Kb;
#pragma unroll
            for (int ms = 0; ms < 4; ++ms) {
                const int ml = wr * 64 + ms * 16 + lgrp * 4;
#pragma unroll
                for (int ns = 0; ns < 4; ++ns) {
                    const int nl = wc * 64 + ns * 16 + lrow;
                    bf16x4 pk;
#pragma unroll
                    for (int j = 0; j < 4; ++j)
                        pk[j] = (bf16_t)((acc[ms][ns][j] + bias[mq * 128 + ml + j]) * scl);
                    *(bf16x4*)&Ct[nl * 136 + ml] = pk;
                }
            }
            __syncthreads();
#pragma unroll
            for (int it = 0; it < 8; ++it) {
                const int idx = it * 256 + t;
                const int token = idx >> 4, oc = idx & 15;
                const bf16x8 vv8 = *(const bf16x8*)&Ct[token * 136 + oc * 8];
                const int head = mq * 2 + (oc >> 3);
                const int d = (oc & 7) * 8;
                *(bf16x8*)(Qk + (((size_t)b * 8 + head) * 1024 + nn0 + token) * 64 + d) = vv8;
            }
        } else {
#pragma unroll
            for (int ms = 0; ms < 4; ++ms) {
                const int ml = wr * 64 + ms * 16 + lgrp * 4;
#pragma unroll
                for (int ns = 0; ns < 4; ++ns) {
                    const int nl = wc * 64 + ns * 16 + lrow;
#pragma unroll
                    for (int j = 0; j < 4; ++j)
                        Ct[(ml + j) * 136 + nl] =
                            (bf16_t)(acc[ms][ns][j] + bias[mq * 128 + ml + j]);
                }
            }
            __syncthreads();
#pragma unroll
            for (int it = 0; it < 8; ++it) {
                const int idx = it * 256 + t;
                const int o = idx >> 4, nc = idx & 15;
                const bf16x8 vv8 = *(const bf16x8*)&Ct[o * 136 + nc * 8];
                const int head = mq * 2 + (o >> 6);
                const int d = o & 63;
                *(bf16x8*)(Vb + (((size_t)b * 8 + head) * 64 + d) * 1024 + nn0 + nc * 8) = vv8;
            }
        }
    } else {
#pragma unroll
        for (int ms = 0; ms < 4; ++ms) {
#pragma unroll
            for (int ns = 0; ns < 4; ++ns) {
                const int c  = m0 + wr * 64 + ms * 16 + lgrp * 4;
                const int np = n0 + wc * 64 + ns * 16 + lrow;
                const int b = np >> 10, n = np & 1023;
#pragma unroll
                for (int j = 0; j < 4; ++j) {
                    const size_t idx = ((size_t)b * 512 + c + j) * 1024 + n;
                    outF[idx] = acc[ms][ns][j] + bias0[c + j] + x0[idx];
                }
            }
        }
    }
}

// ---------------------------------------------------------------------------
// K3: fused attention, 32x32x16 + in-register softmax, NK-SPLIT wave pairs.
// 8 waves = 4 q-chunks (qc=w&3, 32 q each) x 2 nk-halves (half=w>>2).
// Block covers 128 q; grid (64, 8) = 512 blocks -> 4 waves/SIMD.
// __launch_bounds__(512, 2): 2nd arg acts as BLOCKS/CU (CUDA semantics) —
// (512,4) capped VGPR at 64 and spilled to scratch (r13: FETCH 5x, 85us).
// Exact softmax splits over nk: partial O/ts combined via LDS at the end.
// ---------------------------------------------------------------------------
__global__ __launch_bounds__(512, 2) void attn_kernel(
    const bf16_t* __restrict__ Qb, const bf16_t* __restrict__ Kb,
    const bf16_t* __restrict__ Vb, const bf16_t* __restrict__ Bias3,
    bf16_t* __restrict__ Xo)
{
    const int bh = blockIdx.x;
    const int h  = bh & 7;
    const int q0 = blockIdx.y * 128;
    const int t = threadIdx.x;
    const int w = t >> 6, l = t & 63;
    const int qc = w & 3, half = w >> 2;
    const int lq = l & 31, hi = l >> 5;

    __shared__ __align__(16) char smem[35840];
    bf16_t* Ks = (bf16_t*)smem;               // [128][72]
    bf16_t* Vs = (bf16_t*)(smem + 18432);     // [64][136]
    float*  comb = (float*)smem;              // [4][64][33] (reused at end)

    // Q fragments (B-op): col=q=l&31, k-chunk d = dc*16 + hi*8
    const int qrow = q0 + qc * 32 + lq;
    const bf16_t* qbase = Qb + ((size_t)bh * 1024 + qrow) * 64;
    bf16x8 qf[4];
#pragma unroll
    for (int dc = 0; dc < 4; ++dc)
        qf[dc] = *(const bf16x8*)(qbase + dc * 16 + hi * 8);

    // bias base: qt = q0/32 + qc; this wave's kt tiles: it*4 + half*2 + {0,1}
    const bf16_t* bbase = Bias3 +
        ((size_t)((h * 32 + (q0 >> 5) + qc) * 32)) * 1024 + (size_t)l * 16;

    bf16x8 ones;
#pragma unroll
    for (int i = 0; i < 8; ++i) ones[i] = (bf16_t)1.0f;

    f32x16 oacc[2], tsacc;
#pragma unroll
    for (int j = 0; j < 16; ++j) { oacc[0][j] = 0.f; oacc[1][j] = 0.f; tsacc[j] = 0.f; }

    const int sr2 = t >> 3;
    const int sc2 = (t & 7) * 8;
    const bf16_t* Kg = Kb + ((size_t)bh * 1024 + sr2) * 64 + sc2;   // [nk][d]
    const bf16_t* Vg = Vb + ((size_t)bh * 64 + sr2) * 1024 + sc2;   // [d][nk]

    // prologue: prefetch double-tile 0 (K 128 rows, V 128 cols) + bias
    bf16x8 kv0 = *(const bf16x8*)(Kg);
    bf16x8 kv1 = *(const bf16x8*)(Kg + (size_t)64 * 64);
    bf16x8 vv0 = *(const bf16x8*)(Vg);
    bf16x8 vv1 = *(const bf16x8*)(Vg + 64);
    bf16x8 bA[4], bB[4];
#pragma unroll
    for (int k = 0; k < 2; ++k) {
        bA[2 * k]     = *(const bf16x8*)(bbase + (size_t)(half * 2 + k) * 1024);
        bA[2 * k + 1] = *(const bf16x8*)(bbase + (size_t)(half * 2 + k) * 1024 + 8);
    }

    auto dtile = [&](int it, bf16x8 (&bcur)[4], bf16x8 (&bnxt)[4]) {
        const int nk0 = it * 128;
        __syncthreads();                 // prev double-tile's LDS reads done
        *(bf16x8*)&Ks[(sr2) * 72 + sc2]      = kv0;
        *(bf16x8*)&Ks[(64 + sr2) * 72 + sc2] = kv1;
        *(bf16x8*)&Vs[sr2 * 136 + sc2]       = vv0;
        *(bf16x8*)&Vs[sr2 * 136 + 64 + sc2]  = vv1;
        __syncthreads();                 // LDS visible to all waves
        if (it < 7) {                    // prefetch double-tile it+1
            const int nkn = nk0 + 128;
#pragma unroll
            for (int k = 0; k < 2; ++k) {
                const size_t tkn = (size_t)((it + 1) * 4 + half * 2 + k) * 1024;
                bnxt[2 * k]     = *(const bf16x8*)(bbase + tkn);
                bnxt[2 * k + 1] = *(const bf16x8*)(bbase + tkn + 8);
            }
            kv0 = *(const bf16x8*)(Kg + (size_t)nkn * 64);
            kv1 = *(const bf16x8*)(Kg + (size_t)(nkn + 64) * 64);
            vv0 = *(const bf16x8*)(Vg + nkn);
            vv1 = *(const bf16x8*)(Vg + nkn + 64);
        }

#pragma unroll
        for (int ktl = 0; ktl < 2; ++ktl) {
            const int ktloc = half * 64 + ktl * 32;
            // S^T = K Q^T + bias  (C-init from bias fragment regs)
            f32x16 sa;
#pragma unroll
            for (int r = 0; r < 8; ++r) {
                sa[r]     = (float)bcur[2 * ktl][r];
                sa[8 + r] = (float)bcur[2 * ktl + 1][r];
            }
#pragma unroll
            for (int dc = 0; dc < 4; ++dc) {
                const bf16x8 kf = *(const bf16x8*)&Ks[(ktloc + lq) * 72 + dc * 16 + hi * 8];
                sa = MFMA32(kf, qf[dc], sa);
            }
            // p = exp2(s): 16 values; pack into 8 bf16x2 words
            unsigned W00, W01, W10, W11, W20, W21, W30, W31;
            {
                float p[16];
#pragma unroll
                for (int r = 0; r < 16; ++r) p[r] = exp2f(sa[r]);
                bf16x2 tw;
#define PACKW(dst, a, b_) { tw[0] = (bf16_t)p[a]; tw[1] = (bf16_t)p[b_]; \
                            dst = __builtin_bit_cast(unsigned, tw); }
                PACKW(W00, 0, 1)   PACKW(W01, 2, 3)
                PACKW(W10, 4, 5)   PACKW(W11, 6, 7)
                PACKW(W20, 8, 9)   PACKW(W21, 10, 11)
                PACKW(W30, 12, 13) PACKW(W31, 14, 15)
#undef PACKW
            }
            // lane-half exchange into PV B-fragment layout
            asm volatile("v_permlane32_swap_b32 %0, %1" : "+v"(W00), "+v"(W10));
            asm volatile("v_permlane32_swap_b32 %0, %1" : "+v"(W01), "+v"(W11));
            asm volatile("v_permlane32_swap_b32 %0, %1" : "+v"(W20), "+v"(W30));
            asm volatile("v_permlane32_swap_b32 %0, %1" : "+v"(W21), "+v"(W31));
            const bf16x8 pf0 = __builtin_bit_cast(bf16x8, (u32x4){W00, W01, W10, W11});
            const bf16x8 pf1 = __builtin_bit_cast(bf16x8, (u32x4){W20, W21, W30, W31});

            // ts(q) += sum_nk P
            tsacc = MFMA32(ones, pf0, tsacc);
            tsacc = MFMA32(ones, pf1, tsacc);
            // PV: out^T[d][q] += V^T[d][nk] P^T[nk][q]
#pragma unroll
            for (int dh = 0; dh < 2; ++dh) {
                const bf16x8 vf0 = *(const bf16x8*)&Vs[(dh * 32 + lq) * 136 + ktloc + hi * 8];
                const bf16x8 vf1 = *(const bf16x8*)&Vs[(dh * 32 + lq) * 136 + ktloc + 16 + hi * 8];
                oacc[dh] = MFMA32(vf0, pf0, oacc[dh]);
                oacc[dh] = MFMA32(vf1, pf1, oacc[dh]);
            }
        }
    };

    for (int it2 = 0; it2 < 8; it2 += 2) {
        dtile(it2,     bA, bB);
        dtile(it2 + 1, bB, bA);
    }

    // combine nk-halves: waves 4-7 publish partials, waves 0-3 reduce+store
    __syncthreads();                      // all compute done; Ks/Vs free
    if (half == 1) {
        float* p = comb + ((size_t)qc * 64 + l) * 33;
#pragma unroll
        for (int j = 0; j < 16; ++j) { p[j] = oacc[0][j]; p[16 + j] = oacc[1][j]; }
        p[32] = tsacc[0];
    }
    __syncthreads();
    if (half == 0) {
        const float* p = comb + ((size_t)qc * 64 + l) * 33;
#pragma unroll
        for (int j = 0; j < 16; ++j) { oacc[0][j] += p[j]; oacc[1][j] += p[16 + j]; }
        const float inv = 1.0f / (tsacc[0] + p[32]);

        const int b = bh >> 3;
        const int q = q0 + qc * 32 + lq;
        bf16_t* xrow = Xo + ((size_t)b * 1024 + q) * 512 + h * 64;
#pragma unroll
        for (int dh = 0; dh < 2; ++dh)
#pragma unroll
            for (int rr = 0; rr < 4; ++rr) {
                bf16x4 o4;
#pragma unroll
                for (int j = 0; j < 4; ++j)
                    o4[j] = (bf16_t)(oacc[dh][4 * rr + j] * inv);
                *(bf16x4*)(xrow + dh * 32 + 8 * rr + 4 * hi) = o4;
            }
    }
}

// ---------------------------------------------------------------------------
extern "C" void kernel_launch(void* const* d_in, const int* in_sizes, int n_in,
                              void* d_out, int out_size, void* d_ws, size_t ws_size,
                              hipStream_t stream)
{
    const float* x     = (const float*)d_in[0];
    const float* gamma = (const float*)d_in[3];
    const float* beta  = (const float*)d_in[4];
    const float* wq    = (const float*)d_in[5];
    const float* bq    = (const float*)d_in[6];
    const float* wk    = (const float*)d_in[7];
    const float* bk    = (const float*)d_in[8];
    const float* wv    = (const float*)d_in[9];
    const float* bv    = (const float*)d_in[10];
    const float* wp    = (const float*)d_in[11];
    const float* bp    = (const float*)d_in[12];
    const float* pos   = (const float*)d_in[13];
    float* out = (float*)d_out;

    size_t off = 0;
    char* wsb = (char*)d_ws;
    auto alloc = [&](size_t bytes) { char* p = wsb + off; off += bytes; return p; };
    bf16_t* Wqkv  = (bf16_t*)alloc((size_t)1536 * 512 * 2);
    bf16_t* Wp    = (bf16_t*)alloc((size_t)512 * 512 * 2);
    bf16_t* xnT   = (bf16_t*)alloc((size_t)8192 * 512 * 2);
    bf16_t* Qb    = (bf16_t*)alloc((size_t)8192 * 512 * 2);
    bf16_t* Kb    = (bf16_t*)alloc((size_t)8192 * 512 * 2);
    bf16_t* Vb    = (bf16_t*)alloc((size_t)8192 * 512 * 2);
    bf16_t* Xo    = (bf16_t*)alloc((size_t)8192 * 512 * 2);
    bf16_t* Bias3 = (bf16_t*)alloc((size_t)8 * 32 * 32 * 64 * 16 * 2);

    hipLaunchKernelGGL(cast_weights, dim3(256), dim3(256), 0, stream,
                       wq, wk, wv, wp, Wqkv, Wp);
    hipLaunchKernelGGL(bias_kernel, dim3(256), dim3(256), 0, stream, pos, Bias3);
    hipLaunchKernelGGL(gn_kernel, dim3(256), dim3(512), 0, stream,
                       x, gamma, beta, xnT);
    hipLaunchKernelGGL(gemm_bt, dim3(768), dim3(256), 0, stream,
                       Wqkv, xnT, 0, 12, bq, bk, bv,
                       nullptr, nullptr, Qb, Kb, Vb);
    hipLaunchKernelGGL(attn_kernel, dim3(64, 8), dim3(512), 0, stream,
                       Qb, Kb, Vb, Bias3, Xo);
    hipLaunchKernelGGL(gemm_bt, dim3(256), dim3(256), 0, stream,
                       Wp, Xo, 1, 4, bp, nullptr, nullptr,
                       x, out, nullptr, nullptr, nullptr);
}

// Round 15
// 85.884 us; speedup vs baseline: 1.5714x; 1.1425x over previous
//
#include <hip/hip_runtime.h>
#include <hip/hip_bf16.h>
#include <math.h>

typedef __bf16 bf16_t;
typedef __bf16 bf16x8 __attribute__((ext_vector_type(8)));
typedef __bf16 bf16x4 __attribute__((ext_vector_type(4)));
typedef float  f32x4  __attribute__((ext_vector_type(4)));

#define MFMA16(a, b, c) __builtin_amdgcn_mfma_f32_16x16x32_bf16((a), (b), (c), 0, 0, 0)
#define GLDS16(g, s) __builtin_amdgcn_global_load_lds( \
    (const __attribute__((address_space(1))) void*)(g), \
    (__attribute__((address_space(3))) void*)(s), 16, 0, 0)

#define LOG2E 1.4426950408889634f

// ---------------------------------------------------------------------------
// K0: merged PREP kernel — three independent jobs, one launch (they formerly
// serialized on the stream; merged, bias/cast VALU work hides under GN's
// BW-bound streaming).
//   blocks [0,512):   rel-bias precompute -> Bias2 (16x16 fragment order)
//   blocks [512,768): GroupNorm -> xnT
//   blocks [768,896): weight cast fp32->bf16
// ---------------------------------------------------------------------------
__global__ __launch_bounds__(512) void prep_kernel(
    const float* __restrict__ wq, const float* __restrict__ wk,
    const float* __restrict__ wv, const float* __restrict__ wp,
    bf16_t* __restrict__ Wqkv, bf16_t* __restrict__ Wp,
    const float* __restrict__ pos, bf16_t* __restrict__ Bias2,
    const float* __restrict__ x, const float* __restrict__ gamma,
    const float* __restrict__ beta, bf16_t* __restrict__ xnT)
{
    const int blk = blockIdx.x;
    const int t = threadIdx.x;
    __shared__ __align__(16) char pshm[4096];

    if (blk < 512) {
        // ---- rel-bias: Bias2[h][qt(64)][kt(64)][lane(64)][j(4)], *log2e ----
        // q = qt*16 + (l&15), nk = kt*16 + (l>>4)*4 + j   (swapped C-layout)
        bf16_t* ps = (bf16_t*)pshm;     // [32][64]: rows dy=qy..qy+31, dx 0..62
        const int h   = blk >> 6;
        const int qt  = blk & 63;
        const int qy  = qt >> 1;
        const int qxb = (qt & 1) * 16;
        for (int i = t; i < 32 * 63; i += 512) {
            const int r = i / 63, dx = i - r * 63;
            ps[r * 64 + dx] = (bf16_t)(pos[h * 3969 + (qy + r) * 63 + dx] * LOG2E);
        }
        __syncthreads();
        bf16_t* outb = Bias2 + (((size_t)h * 64 + qt) * 64) * 256;
#pragma unroll
        for (int it = 0; it < 8; ++it) {
            const int idx = t + it * 512;        // [0, 4096) = kt*64 + lane
            const int kt = idx >> 6, l = idx & 63;
            const int qx  = qxb + (l & 15);      // col = q
            const int nk0 = kt * 16 + (l >> 4) * 4;
            const int ky = nk0 >> 5;
            const int kx0 = nk0 & 31;
            const int r = 31 - ky;
            const int dx0 = qx - kx0 + 31;
            bf16x4 o;
#pragma unroll
            for (int j = 0; j < 4; ++j) o[j] = ps[r * 64 + dx0 - j];
            *(bf16x4*)(outb + (size_t)idx * 4) = o;
        }
    } else if (blk < 768) {
        // ---- GroupNorm, single-sweep register-resident ----
        float* red = (float*)pshm;
        const int bgn = blk - 512;
        const int b = bgn >> 5, g = bgn & 31;
        const int hi = t >> 8, tl = t & 255;
        const float* base = x + ((size_t)b * 512 + g * 16) * 1024;

        f32x4 v[8];
        float s = 0.f, s2 = 0.f;
#pragma unroll
        for (int it = 0; it < 8; ++it) {
            v[it] = *(const f32x4*)(base + (size_t)hi * 8192 + it * 1024 + tl * 4);
#pragma unroll
            for (int j = 0; j < 4; ++j) { s += v[it][j]; s2 += v[it][j] * v[it][j]; }
        }
#pragma unroll
        for (int m = 1; m < 64; m <<= 1) { s += __shfl_xor(s, m); s2 += __shfl_xor(s2, m); }
        const int w = t >> 6;
        if ((t & 63) == 0) { red[w] = s; red[8 + w] = s2; }
        __syncthreads();
        s = 0.f; s2 = 0.f;
#pragma unroll
        for (int i = 0; i < 8; ++i) { s += red[i]; s2 += red[8 + i]; }
        const float mean = s * (1.f / 16384.f);
        const float var  = fmaxf(s2 * (1.f / 16384.f) - mean * mean, 0.f);
        const float rstd = rsqrtf(var + 1e-6f);

        float ga[8], be[8];
#pragma unroll
        for (int it = 0; it < 8; ++it) {
            const int gc = g * 16 + hi * 8 + it;
            ga[it] = gamma[gc] * rstd;
            be[it] = beta[gc] - mean * ga[it];
        }
#pragma unroll
        for (int j = 0; j < 4; ++j) {
            bf16x8 o;
#pragma unroll
            for (int it = 0; it < 8; ++it)
                o[it] = (bf16_t)(v[it][j] * ga[it] + be[it]);
            *(bf16x8*)(xnT + ((size_t)b * 1024 + tl * 4 + j) * 512 + g * 16 + hi * 8) = o;
        }
    } else {
        // ---- weight cast fp32 -> bf16 ----
        const int i = ((blk - 768) * 512 + t) * 4;
#pragma unroll
        for (int j = 0; j < 4; ++j) {
            Wqkv[i + j]          = (bf16_t)wq[i + j];
            Wqkv[262144 + i + j] = (bf16_t)wk[i + j];
            Wqkv[524288 + i + j] = (bf16_t)wv[i + j];
            Wp[i + j]            = (bf16_t)wp[i + j];
        }
    }
}

// ---------------------------------------------------------------------------
// K2/K4: GEMM (unchanged — 3-buffer ring + counted vmcnt).
// ---------------------------------------------------------------------------
__global__ __launch_bounds__(256) void gemm_bt(
    const bf16_t* __restrict__ A, const bf16_t* __restrict__ Bt, int mode,
    int mtiles,
    const float* __restrict__ bias0, const float* __restrict__ bias1,
    const float* __restrict__ bias2,
    const float* __restrict__ x0, float* __restrict__ outF,
    bf16_t* __restrict__ Qb, bf16_t* __restrict__ Kb, bf16_t* __restrict__ Vb)
{
    const int K  = 512;
    const int g  = blockIdx.x;
    const int xcd = g & 7;
    const int i_  = g >> 3;
    const int m_idx = i_ % mtiles;
    const int n_idx = xcd * 8 + i_ / mtiles;
    const int m0 = m_idx * 128;
    const int n0 = n_idx * 128;
    const int t = threadIdx.x;
    const int l = t & 63, w = t >> 6;
    const int wr = w >> 1, wc = w & 1;
    const int lrow = l & 15, lgrp = l >> 4;

    __shared__ __align__(16) char smem_raw[49152];
    bf16_t* Ct = (bf16_t*)smem_raw;           // [128][136] (34816 B)

    f32x4 acc[4][4];
#pragma unroll
    for (int i = 0; i < 4; ++i)
#pragma unroll
        for (int j = 0; j < 4; ++j) acc[i][j] = (f32x4){0.f, 0.f, 0.f, 0.f};

    const bf16_t* gA0 = A  + (size_t)(m0 + w * 16 + (l >> 2)) * K + (l & 3) * 8;
    const bf16_t* gA1 = gA0 + (size_t)64 * K;
    const bf16_t* gB0 = Bt + (size_t)(n0 + w * 16 + (l >> 2)) * K + (l & 3) * 8;
    const bf16_t* gB1 = gB0 + (size_t)64 * K;

#define STAGE(s, k0) do {                                                   \
    bf16_t* As_ = (bf16_t*)(smem_raw + (s) * 16384);                        \
    bf16_t* Bs_ = (bf16_t*)(smem_raw + (s) * 16384 + 8192);                 \
    GLDS16(gA0 + (k0), As_ + w * 512);                                      \
    GLDS16(gA1 + (k0), As_ + 2048 + w * 512);                               \
    GLDS16(gB0 + (k0), Bs_ + w * 512);                                      \
    GLDS16(gB1 + (k0), Bs_ + 2048 + w * 512); } while (0)

    STAGE(0, 0);
    STAGE(1, 32);

#pragma unroll
    for (int tk = 0; tk < 16; ++tk) {
        if (tk < 15) asm volatile("s_waitcnt vmcnt(4)" ::: "memory");
        else         asm volatile("s_waitcnt vmcnt(0)" ::: "memory");
        __builtin_amdgcn_s_barrier();
        __builtin_amdgcn_sched_barrier(0);
        if (tk + 2 < 16) STAGE((tk + 2) % 3, (tk + 2) * 32);
        const bf16_t* Asb = (const bf16_t*)(smem_raw + (tk % 3) * 16384);
        const bf16_t* Bsb = Asb + 4096;
        bf16x8 af[4], bfr[4];
#pragma unroll
        for (int ms = 0; ms < 4; ++ms)
            af[ms] = *(const bf16x8*)&Asb[(wr * 64 + ms * 16 + lrow) * 32 + lgrp * 8];
#pragma unroll
        for (int ns = 0; ns < 4; ++ns)
            bfr[ns] = *(const bf16x8*)&Bsb[(wc * 64 + ns * 16 + lrow) * 32 + lgrp * 8];
        __builtin_amdgcn_s_setprio(1);
#pragma unroll
        for (int ms = 0; ms < 4; ++ms)
#pragma unroll
            for (int ns = 0; ns < 4; ++ns)
                acc[ms][ns] = MFMA16(af[ms], bfr[ns], acc[ms][ns]);
        __builtin_amdgcn_s_setprio(0);
    }
#undef STAGE

    if (mode == 0) {
        const int which = m0 >> 9;
        const int mq = (m0 >> 7) & 3;
        const float* bias = (which == 0) ? bias0 : (which == 1) ? bias1 : bias2;
        const float scl = (which == 0) ? 0.125f * LOG2E : 1.0f;
        const int b   = n_idx >> 3;
        const int nn0 = (n_idx & 7) * 128;

        __syncthreads();
        if (which < 2) {
            bf16_t* Qk = (which == 0) ? Qb : Kb;
#pragma unroll
            for (int ms = 0; ms < 4; ++ms) {
                const int ml = wr * 64 + ms * 16 + lgrp * 4;
#pragma unroll
                for (int ns = 0; ns < 4; ++ns) {
                    const int nl = wc * 64 + ns * 16 + lrow;
                    bf16x4 pk;
#pragma unroll
                    for (int j = 0; j < 4; ++j)
                        pk[j] = (bf16_t)((acc[ms][ns][j] + bias[mq * 128 + ml + j]) * scl);
                    *(bf16x4*)&Ct[nl * 136 + ml] = pk;
                }
            }
            __syncthreads();
#pragma unroll
            for (int it = 0; it < 8; ++it) {
                const int idx = it * 256 + t;
                const int token = idx >> 4, oc = idx & 15;
                const bf16x8 vv8 = *(const bf16x8*)&Ct[token * 136 + oc * 8];
                const int head = mq * 2 + (oc >> 3);
                const int d = (oc & 7) * 8;
                *(bf16x8*)(Qk + (((size_t)b * 8 + head) * 1024 + nn0 + token) * 64 + d) = vv8;
            }
        } else {
#pragma unroll
            for (int ms = 0; ms < 4; ++ms) {
                const int ml = wr * 64 + ms * 16 + lgrp * 4;
#pragma unroll
                for (int ns = 0; ns < 4; ++ns) {
                    const int nl = wc * 64 + ns * 16 + lrow;
#pragma unroll
                    for (int j = 0; j < 4; ++j)
                        Ct[(ml + j) * 136 + nl] =
                            (bf16_t)(acc[ms][ns][j] + bias[mq * 128 + ml + j]);
                }
            }
            __syncthreads();
#pragma unroll
            for (int it = 0; it < 8; ++it) {
                const int idx = it * 256 + t;
                const int o = idx >> 4, nc = idx & 15;
                const bf16x8 vv8 = *(const bf16x8*)&Ct[o * 136 + nc * 8];
                const int head = mq * 2 + (o >> 6);
                const int d = o & 63;
                *(bf16x8*)(Vb + (((size_t)b * 8 + head) * 64 + d) * 1024 + nn0 + nc * 8) = vv8;
            }
        }
    } else {
#pragma unroll
        for (int ms = 0; ms < 4; ++ms) {
#pragma unroll
            for (int ns = 0; ns < 4; ++ns) {
                const int c  = m0 + wr * 64 + ms * 16 + lgrp * 4;
                const int np = n0 + wc * 64 + ns * 16 + lrow;
                const int b = np >> 10, n = np & 1023;
#pragma unroll
                for (int j = 0; j < 4; ++j) {
                    const size_t idx = ((size_t)b * 512 + c + j) * 1024 + n;
                    outF[idx] = acc[ms][ns][j] + bias0[c + j] + x0[idx];
                }
            }
        }
    }
}

// ---------------------------------------------------------------------------
// K3: fused attention — r11's proven best variant (16x16 MFMA, swapped-QK,
// max-free base-2 softmax, 8-wave/128q blocks, double-tile staging, MFMA
// row-sum, no setprio).  42.7us / 33% occupancy measured.
// Grid: x = bh (XCD ~ h -> K/V+bias L2-resident), y = q-tile/128.
// ---------------------------------------------------------------------------
__global__ __launch_bounds__(512) void attn_kernel(
    const bf16_t* __restrict__ Qb, const bf16_t* __restrict__ Kb,
    const bf16_t* __restrict__ Vb, const bf16_t* __restrict__ Bias2,
    bf16_t* __restrict__ Xo)
{
    const int bh = blockIdx.x;
    const int h  = bh & 7;
    const int q0 = blockIdx.y * 128;
    const int t = threadIdx.x;
    const int w = t >> 6, l = t & 63;
    const int lrow = l & 15, lgrp = l >> 4;

    __shared__ __align__(16) bf16_t Ks[128][72];     // [nk][d]
    __shared__ __align__(16) bf16_t Vs[64][136];     // [d][nk]
    __shared__ __align__(16) bf16_t Ps[8][16][72];   // per-wave [q][nk]

    const int qrow = q0 + w * 16 + lrow;
    const bf16_t* qbase = Qb + ((size_t)bh * 1024 + qrow) * 64;
    const bf16x8 qf0 = *(const bf16x8*)(qbase + lgrp * 8);
    const bf16x8 qf1 = *(const bf16x8*)(qbase + 32 + lgrp * 8);

    const bf16_t* bb = Bias2 + (((size_t)h * 64 + (q0 >> 4) + w) * 64) * 256;

    bf16x8 ones;
#pragma unroll
    for (int i = 0; i < 8; ++i) ones[i] = (bf16_t)1.0f;

    f32x4 oacc[4], tsacc = (f32x4){0.f, 0.f, 0.f, 0.f};
#pragma unroll
    for (int j = 0; j < 4; ++j) oacc[j] = (f32x4){0.f, 0.f, 0.f, 0.f};

    const int sr2 = t >> 3;
    const int sc2 = (t & 7) * 8;
    const bf16_t* Kg = Kb + ((size_t)bh * 1024 + sr2) * 64 + sc2;   // [nk][d]
    const bf16_t* Vg = Vb + ((size_t)bh * 64 + sr2) * 1024 + sc2;   // [d][nk]

    // prologue: prefetch double-tile 0 (K 128 rows, V 128 cols, bias x8)
    bf16x8 kv0 = *(const bf16x8*)(Kg);
    bf16x8 kv1 = *(const bf16x8*)(Kg + (size_t)64 * 64);
    bf16x8 vv0 = *(const bf16x8*)(Vg);
    bf16x8 vv1 = *(const bf16x8*)(Vg + 64);
    bf16x4 bA[8], bB[8];
#pragma unroll
    for (int k = 0; k < 8; ++k)
        bA[k] = *(const bf16x4*)(bb + (size_t)(k * 64 + l) * 4);

    auto dtile = [&](int it, bf16x4 (&bcur)[8], bf16x4 (&bnxt)[8]) {
        const int nk0 = it * 128;
        __syncthreads();                 // prev double-tile's LDS reads done
        *(bf16x8*)&Ks[sr2][sc2]      = kv0;
        *(bf16x8*)&Ks[64 + sr2][sc2] = kv1;
        *(bf16x8*)&Vs[sr2][sc2]      = vv0;
        *(bf16x8*)&Vs[sr2][64 + sc2] = vv1;
        __syncthreads();                 // LDS visible to all waves
        if (it < 7) {                    // prefetch double-tile it+1
            const int nkn = nk0 + 128;
#pragma unroll
            for (int k = 0; k < 8; ++k)
                bnxt[k] = *(const bf16x4*)(bb + (size_t)((((nkn >> 4)) + k) * 64 + l) * 4);
            kv0 = *(const bf16x8*)(Kg + (size_t)nkn * 64);
            kv1 = *(const bf16x8*)(Kg + (size_t)(nkn + 64) * 64);
            vv0 = *(const bf16x8*)(Vg + nkn);
            vv1 = *(const bf16x8*)(Vg + nkn + 64);
        }

#pragma unroll
        for (int st = 0; st < 2; ++st) {
            // S^T = K Q^T (+bias from regs):  D[row = nk_local][col = q]
            f32x4 s[4];
#pragma unroll
            for (int ns = 0; ns < 4; ++ns) {
                const bf16x4 bc = bcur[st * 4 + ns];
                f32x4 z = (f32x4){(float)bc[0], (float)bc[1],
                                  (float)bc[2], (float)bc[3]};
                const bf16x8 kf0 = *(const bf16x8*)&Ks[st * 64 + ns * 16 + lrow][lgrp * 8];
                const bf16x8 kf1 = *(const bf16x8*)&Ks[st * 64 + ns * 16 + lrow][32 + lgrp * 8];
                z = MFMA16(kf0, qf0, z);
                z = MFMA16(kf1, qf1, z);
                s[ns] = z;
            }
            // p = exp2(s); pack to Ps[q][nk]  (row-sum handled by MFMA below)
#pragma unroll
            for (int ns = 0; ns < 4; ++ns) {
                bf16x4 pk;
                pk[0] = (bf16_t)exp2f(s[ns][0]);
                pk[1] = (bf16_t)exp2f(s[ns][1]);
                pk[2] = (bf16_t)exp2f(s[ns][2]);
                pk[3] = (bf16_t)exp2f(s[ns][3]);
                *(bf16x4*)&Ps[w][lrow][ns * 16 + lgrp * 4] = pk;
            }
            const bf16x8 pf0 = *(const bf16x8*)&Ps[w][lrow][lgrp * 8];
            const bf16x8 pf1 = *(const bf16x8*)&Ps[w][lrow][32 + lgrp * 8];
            // ts(q) += sum_nk P  (ones-A MFMA: every row of D = row-sum)
            tsacc = MFMA16(ones, pf0, tsacc);
            tsacc = MFMA16(ones, pf1, tsacc);
            // PV:  out^T[d][q] += V^T[d][nk] * P^T[nk][q]
#pragma unroll
            for (int ds = 0; ds < 4; ++ds) {
                const bf16x8 vf0 = *(const bf16x8*)&Vs[ds * 16 + lrow][st * 64 + lgrp * 8];
                const bf16x8 vf1 = *(const bf16x8*)&Vs[ds * 16 + lrow][st * 64 + 32 + lgrp * 8];
                oacc[ds] = MFMA16(vf0, pf0, oacc[ds]);
                oacc[ds] = MFMA16(vf1, pf1, oacc[ds]);
            }
        }
    };

    for (int it2 = 0; it2 < 8; it2 += 2) {
        dtile(it2,     bA, bB);
        dtile(it2 + 1, bB, bA);
    }

    // tsacc holds full ts(q) in every element for this lane's q = lrow
    const float inv = 1.0f / tsacc[0];

    const int b = bh >> 3;
    const int q = q0 + w * 16 + lrow;
    bf16_t* xrow = Xo + ((size_t)b * 1024 + q) * 512 + h * 64;
#pragma unroll
    for (int ds = 0; ds < 4; ++ds) {
        bf16x4 o4;
#pragma unroll
        for (int j = 0; j < 4; ++j) o4[j] = (bf16_t)(oacc[ds][j] * inv);
        *(bf16x4*)(xrow + ds * 16 + lgrp * 4) = o4;
    }
}

// ---------------------------------------------------------------------------
extern "C" void kernel_launch(void* const* d_in, const int* in_sizes, int n_in,
                              void* d_out, int out_size, void* d_ws, size_t ws_size,
                              hipStream_t stream)
{
    const float* x     = (const float*)d_in[0];
    const float* gamma = (const float*)d_in[3];
    const float* beta  = (const float*)d_in[4];
    const float* wq    = (const float*)d_in[5];
    const float* bq    = (const float*)d_in[6];
    const float* wk    = (const float*)d_in[7];
    const float* bk    = (const float*)d_in[8];
    const float* wv    = (const float*)d_in[9];
    const float* bv    = (const float*)d_in[10];
    const float* wp    = (const float*)d_in[11];
    const float* bp    = (const float*)d_in[12];
    const float* pos   = (const float*)d_in[13];
    float* out = (float*)d_out;

    size_t off = 0;
    char* wsb = (char*)d_ws;
    auto alloc = [&](size_t bytes) { char* p = wsb + off; off += bytes; return p; };
    bf16_t* Wqkv  = (bf16_t*)alloc((size_t)1536 * 512 * 2);
    bf16_t* Wp    = (bf16_t*)alloc((size_t)512 * 512 * 2);
    bf16_t* xnT   = (bf16_t*)alloc((size_t)8192 * 512 * 2);
    bf16_t* Qb    = (bf16_t*)alloc((size_t)8192 * 512 * 2);
    bf16_t* Kb    = (bf16_t*)alloc((size_t)8192 * 512 * 2);
    bf16_t* Vb    = (bf16_t*)alloc((size_t)8192 * 512 * 2);
    bf16_t* Xo    = (bf16_t*)alloc((size_t)8192 * 512 * 2);
    bf16_t* Bias2 = (bf16_t*)alloc((size_t)8 * 64 * 64 * 64 * 4 * 2);

    hipLaunchKernelGGL(prep_kernel, dim3(896), dim3(512), 0, stream,
                       wq, wk, wv, wp, Wqkv, Wp, pos, Bias2,
                       x, gamma, beta, xnT);
    hipLaunchKernelGGL(gemm_bt, dim3(768), dim3(256), 0, stream,
                       Wqkv, xnT, 0, 12, bq, bk, bv,
                       nullptr, nullptr, Qb, Kb, Vb);
    hipLaunchKernelGGL(attn_kernel, dim3(64, 8), dim3(512), 0, stream,
                       Qb, Kb, Vb, Bias2, Xo);
    hipLaunchKernelGGL(gemm_bt, dim3(256), dim3(256), 0, stream,
                       Wp, Xo, 1, 4, bp, nullptr, nullptr,
                       x, out, nullptr, nullptr, nullptr);
}